// Round 2
// baseline (46100.302 us; speedup 1.0000x reference)
//
#include <hip/hip_runtime.h>
#include <cstdint>
#include <cstddef>

#define NV    32768
#define EMB   512
#define DEG   32
#define NC    50
#define H3DIM 281
#define MT    4096            // M-tile rows for the tiled MLP

// ---------------- threefry2x32, key = jax.random.key(42) -> (0, 42) ----------------
__device__ __forceinline__ void threefry(unsigned x0, unsigned x1,
                                         unsigned& y0, unsigned& y1) {
  const unsigned ks0 = 0u, ks1 = 42u, ks2 = 0x1BD11BDAu ^ 42u;
  x0 += ks0; x1 += ks1;
#define TFR(r) { x0 += x1; x1 = (x1 << (r)) | (x1 >> (32 - (r))); x1 ^= x0; }
  TFR(13) TFR(15) TFR(26) TFR(6)  x0 += ks1; x1 += ks2 + 1u;
  TFR(17) TFR(29) TFR(16) TFR(24) x0 += ks2; x1 += ks0 + 2u;
  TFR(13) TFR(15) TFR(26) TFR(6)  x0 += ks0; x1 += ks1 + 3u;
  TFR(17) TFR(29) TFR(16) TFR(24) x0 += ks1; x1 += ks2 + 4u;
  TFR(13) TFR(15) TFR(26) TFR(6)  x0 += ks2; x1 += ks0 + 5u;
#undef TFR
  y0 = x0; y1 = x1;
}

// partitionable threefry (jax >= 0.5 default): element i -> threefry(key, (i>>32, i&~0u)),
// 32-bit output = bits1 ^ bits2. Then jax _uniform + gumbel transform.
__device__ __forceinline__ float gumbel_at(unsigned idx) {
  unsigned y0, y1;
  threefry(0u, idx, y0, y1);          // hi32(idx)=0 for idx < 2^32
  unsigned bits = y0 ^ y1;
  unsigned fb = (bits >> 9) | 0x3F800000u;
  float f = __uint_as_float(fb) - 1.0f;
  float u = fmaxf(f, 1.17549435e-38f);  // max(tiny, f*(1-tiny)+tiny) == max(f, tiny) in f32
  return -logf(-logf(u));
}

// ---------------- fp32 tiled GEMM: C = act(A[MxK] @ W[KxN] + b) ----------------
// k-ascending single-accumulator FMA per output element (closest to CPU BLAS order).
#define TILE 64
#define BK   16
__global__ __launch_bounds__(256) void gemm_bias_act(
    const float* __restrict__ A, const float* __restrict__ W,
    const float* __restrict__ bias, float* __restrict__ C,
    int M, int N, int K, int act) {
  __shared__ float As[BK][TILE + 1];  // As[k][m]
  __shared__ float Bs[BK][TILE];      // Bs[k][n]
  int tid = threadIdx.x;
  int bm = blockIdx.y * TILE;
  int bn = blockIdx.x * TILE;
  int tx = tid & 15, ty = tid >> 4;   // 16x16 threads, 4x4 micro-tile each
  int ar = tid >> 2;                  // 0..63
  int ac = (tid & 3) * 4;             // 0,4,8,12
  int br = tid >> 4;                  // 0..15
  int bc = (tid & 15) * 4;            // 0..60
  float acc[4][4] = {{0.f,0.f,0.f,0.f},{0.f,0.f,0.f,0.f},{0.f,0.f,0.f,0.f},{0.f,0.f,0.f,0.f}};

  for (int k0 = 0; k0 < K; k0 += BK) {
    {
      int gk = k0 + ac;
      const float* ap = A + (size_t)(bm + ar) * K + gk;
      float a0, a1, a2, a3;
      if (((K & 3) == 0) && (gk + 3 < K)) {
        float4 av = *(const float4*)ap;
        a0 = av.x; a1 = av.y; a2 = av.z; a3 = av.w;
      } else {
        a0 = (gk + 0 < K) ? ap[0] : 0.f;
        a1 = (gk + 1 < K) ? ap[1] : 0.f;
        a2 = (gk + 2 < K) ? ap[2] : 0.f;
        a3 = (gk + 3 < K) ? ap[3] : 0.f;
      }
      As[ac + 0][ar] = a0; As[ac + 1][ar] = a1;
      As[ac + 2][ar] = a2; As[ac + 3][ar] = a3;
    }
    {
      int gr = k0 + br;
      int gc = bn + bc;
      const float* bp = W + (size_t)gr * N + gc;
      float b0 = 0.f, b1 = 0.f, b2 = 0.f, b3 = 0.f;
      if (gr < K) {
        if (((N & 3) == 0) && (gc + 3 < N)) {
          float4 bv = *(const float4*)bp;
          b0 = bv.x; b1 = bv.y; b2 = bv.z; b3 = bv.w;
        } else {
          b0 = (gc + 0 < N) ? bp[0] : 0.f;
          b1 = (gc + 1 < N) ? bp[1] : 0.f;
          b2 = (gc + 2 < N) ? bp[2] : 0.f;
          b3 = (gc + 3 < N) ? bp[3] : 0.f;
        }
      }
      Bs[br][bc + 0] = b0; Bs[br][bc + 1] = b1;
      Bs[br][bc + 2] = b2; Bs[br][bc + 3] = b3;
    }
    __syncthreads();
#pragma unroll
    for (int kk = 0; kk < BK; ++kk) {
      float a[4], b[4];
#pragma unroll
      for (int i = 0; i < 4; ++i) a[i] = As[kk][ty * 4 + i];
#pragma unroll
      for (int j = 0; j < 4; ++j) b[j] = Bs[kk][tx * 4 + j];
#pragma unroll
      for (int i = 0; i < 4; ++i)
#pragma unroll
        for (int j = 0; j < 4; ++j)
          acc[i][j] = fmaf(a[i], b[j], acc[i][j]);
    }
    __syncthreads();
  }
#pragma unroll
  for (int i = 0; i < 4; ++i) {
    int row = bm + ty * 4 + i;
#pragma unroll
    for (int j = 0; j < 4; ++j) {
      int cn = bn + tx * 4 + j;
      if (cn < N) {
        float v = acc[i][j] + bias[cn];
        if (act) v = (v >= 0.f) ? v : 0.01f * v;
        C[(size_t)row * N + cn] = v;
      }
    }
  }
}

// ---------------- sequential coloring: one wave, colors in LDS, inline gumbel ----------------
__global__ __launch_bounds__(64) void color_seq(
    const float* __restrict__ logits, const int* __restrict__ adj,
    const int* __restrict__ order, float* __restrict__ out,
    int* __restrict__ col_i32, float* __restrict__ scal, int* __restrict__ icnt) {
  __shared__ unsigned char col[NV];  // 32 KB; 0xFF == unassigned (-1)
  int lane = threadIdx.x;
  for (int i = lane; i < NV; i += 64) col[i] = 0xFFu;
  __syncthreads();
  int v0 = order[0];
  if (lane == 0) col[v0] = 0u;
  unsigned long long used = 1ULL;  // color 0 assigned to first vertex
  float logp = 0.0f;
  const float C0 = logf(1e-8f);

  // 1-deep prefetch of logits/adj (addresses 2-deep via v_nn)
  int v_n = order[1];
  int v_nn = order[2];
  float lg_n = (lane < NC) ? logits[v_n * NC + lane] : -INFINITY;
  int nb_n = (lane < DEG) ? adj[v_n * DEG + lane] : 0;

  for (int step = 1; step < NV; ++step) {
    int v = v_n;
    float lg = lg_n;
    int nb = nb_n;
    // gumbel row step-1, computed inline (pure ALU)
    float gb = (lane < NC) ? gumbel_at((unsigned)((step - 1) * NC + lane)) : 0.0f;
    if (step + 1 < NV) {
      int vn = v_nn;
      lg_n = (lane < NC) ? logits[vn * NC + lane] : -INFINITY;
      nb_n = (lane < DEG) ? adj[vn * DEG + lane] : 0;
      v_n = vn;
      v_nn = (step + 2 < NV) ? order[step + 2] : 0;
    }
    __syncthreads();  // order previous col[] write before this gather
    int nc = col[nb];
    unsigned long long bit =
        (lane < DEG && nc != 0xFF) ? (1ULL << nc) : 0ULL;
#pragma unroll
    for (int off = 1; off < 64; off <<= 1) bit |= __shfl_xor(bit, off);
    bool masked = (bit >> lane) & 1ULL;
    float x = (lane < NC && !masked) ? lg : -INFINITY;
    float y = x + gb;  // -inf stays -inf
    float ym = y;
#pragma unroll
    for (int off = 1; off < 64; off <<= 1) ym = fmaxf(ym, __shfl_xor(ym, off));
    unsigned long long eq = __ballot(y == ym);
    int chosen = __ffsll((unsigned long long)eq) - 1;  // first-index tie-break
    float xm = x;
#pragma unroll
    for (int off = 1; off < 64; off <<= 1) xm = fmaxf(xm, __shfl_xor(xm, off));
    float ex = expf(x - xm);  // x=-inf -> 0
    float S = ex;
#pragma unroll
    for (int off = 1; off < 64; off <<= 1) S += __shfl_xor(S, off);
    float ec = __shfl(ex, chosen);
    float p = ec / S;
    logp = (logp + logf(p + 1e-8f)) - C0;  // exact reference op order
    used |= (1ULL << chosen);
    if (lane == 0) col[v] = (unsigned char)chosen;
  }
  __syncthreads();
  for (int i = lane; i < NV; i += 64) {
    int c = (int)col[i];
    col_i32[i] = c;
    out[i] = (float)c;
  }
  if (lane == 0) {
    scal[0] = logp;
    icnt[0] = __popcll(used);  // n_used
    icnt[1] = 0;               // violation counter init (ws is poisoned)
  }
}

// ---------------- violation count ----------------
__global__ void violation_kernel(const int* __restrict__ col,
                                 const int* __restrict__ adj,
                                 int* __restrict__ cnt) {
  int idx = blockIdx.x * 256 + threadIdx.x;  // exactly NV*DEG threads
  int v = idx >> 5;
  int same = (col[adj[idx]] == col[v]) ? 1 : 0;
  unsigned long long b = __ballot(same);
  if ((threadIdx.x & 63) == 0) atomicAdd(cnt, __popcll(b));
}

// ---------------- finalize loss ----------------
__global__ void finalize_kernel(const float* __restrict__ scal,
                                const int* __restrict__ icnt,
                                float* __restrict__ out) {
  float logp = scal[0];
  float nused = (float)icnt[0];
  float ratio = (float)icnt[1] / 1048576.0f;  // exact: count/2^20
  float cost = nused + ratio * 100.0f;
  float conf = logp / 32768.0f;
  out[NV] = cost * conf;
}

// ---------------- launch ----------------
extern "C" void kernel_launch(void* const* d_in, const int* in_sizes, int n_in,
                              void* d_out, int out_size, void* d_ws, size_t ws_size,
                              hipStream_t stream) {
  const float* emb  = (const float*)d_in[0];   // [NV, EMB]
  const int*   adj  = (const int*)d_in[1];     // [NV, DEG]
  const int*   ord  = (const int*)d_in[2];     // [NV]
  const float* W1   = (const float*)d_in[3];   // [EMB, EMB]
  const float* b1   = (const float*)d_in[4];
  const float* W2   = (const float*)d_in[5];
  const float* b2   = (const float*)d_in[6];
  const float* W3   = (const float*)d_in[7];   // [EMB, H3DIM]
  const float* b3   = (const float*)d_in[8];
  const float* W4   = (const float*)d_in[9];   // [H3DIM, NC]
  const float* b4   = (const float*)d_in[10];
  float* out = (float*)d_out;

  // workspace layout (< 29 MB total):
  char* ws = (char*)d_ws;
  float* logit = (float*)(ws);                                   // 6.55 MB
  int*   col32 = (int*)  (ws + (size_t)7 * 1024 * 1024);         // 128 KB
  float* scal  = (float*)(ws + (size_t)7 * 1024 * 1024 + 192 * 1024);
  int*   icnt  = (int*)  (ws + (size_t)7 * 1024 * 1024 + 192 * 1024 + 256);
  float* H1t   = (float*)(ws + (size_t)8  * 1024 * 1024);        // 8 MB (MT x 512)
  float* H2t   = (float*)(ws + (size_t)16 * 1024 * 1024);        // 8 MB (MT x 512)
  float* H3t   = (float*)(ws + (size_t)24 * 1024 * 1024);        // 4.6 MB (MT x 281)

  // batched MLP, M-tiled (identical per-element arithmetic to a full-M pass)
  dim3 blk(256);
  for (int t = 0; t < NV / MT; ++t) {
    const float* embT = emb + (size_t)t * MT * EMB;
    float* logT = logit + (size_t)t * MT * NC;
    gemm_bias_act<<<dim3(EMB / TILE, MT / TILE), blk, 0, stream>>>(
        embT, W1, b1, H1t, MT, EMB, EMB, 1);
    gemm_bias_act<<<dim3(EMB / TILE, MT / TILE), blk, 0, stream>>>(
        H1t, W2, b2, H2t, MT, EMB, EMB, 1);
    gemm_bias_act<<<dim3((H3DIM + TILE - 1) / TILE, MT / TILE), blk, 0, stream>>>(
        H2t, W3, b3, H3t, MT, H3DIM, EMB, 1);
    gemm_bias_act<<<dim3(1, MT / TILE), blk, 0, stream>>>(
        H3t, W4, b4, logT, MT, NC, H3DIM, 0);
  }

  // sequential greedy coloring (single wave, colors in LDS, inline gumbel)
  color_seq<<<1, 64, 0, stream>>>(logit, adj, ord, out, col32, scal, icnt);

  // violation ratio + loss
  violation_kernel<<<(NV * DEG) / 256, 256, 0, stream>>>(col32, adj, icnt + 1);
  finalize_kernel<<<1, 1, 0, stream>>>(scal, icnt, out);
}